// Round 8
// baseline (255.154 us; speedup 1.0000x reference)
//
#include <hip/hip_runtime.h>
#include <hip/hip_bf16.h>
#include <cstdint>
#include <cstddef>

// Problem constants
#define CNU 500000      // item id offset
#define CB  65536       // batch
#define CE  128         // embedding dim
#define CF  172         // feature dim
#define EV  128         // events per block (8 M-tiles of 16) — halves weight traffic vs 64
#define MT  8           // M-tiles

typedef unsigned short ushort_t;
typedef __attribute__((ext_vector_type(8))) short b8;    // 8 x bf16
typedef __attribute__((ext_vector_type(4))) short b4;    // 4 x bf16
typedef __attribute__((ext_vector_type(4))) float f4;    // MFMA accumulator
typedef __attribute__((ext_vector_type(4))) float f32x4;

#define MFMA16(a,b,c) __builtin_amdgcn_mfma_f32_16x16x32_bf16((a),(b),(c),0,0,0)

// Non-temporal loads/stores for the read-once gather stream (neutral but harmless).
#define NTL4(p)   __builtin_nontemporal_load((const f32x4*)(p))
#define NTLI(p)   __builtin_nontemporal_load(p)
#define NTS(v, p) __builtin_nontemporal_store((v), (p))

// ---- packed weight layout in ws (ushort elements), B-fragment order:
// frag(nt,kt): lane l holds B[k=kt*32+(l>>4)*8+j][n=nt*16+(l&15)], j=0..7
#define FRAG 512
#define U_KT 18                   // 14 k-tiles wih (K pad 448) + 4 whh
#define U_NT 24
#define U_SZ (U_NT*U_KT*FRAG)
#define PU_OFF 0
#define PI_OFF U_SZ
#define PG_OFF (2*U_SZ)
#define G_SZ (8*8*FRAG)
#define PP_OFF (PG_OFF + G_SZ)
#define P_SZ (8*4*FRAG)

// XOR-swizzle on 16B granules, both write and read sides (T2 discipline).
#define SWZ(r, c) ((c) ^ (((r) & 7) << 3))
#define AFRAG(T, r, c) (*(const b8*)&(T)[(r)][SWZ((r), (c))])

__device__ __forceinline__ unsigned pk2bf(float a, float b) {
  __hip_bfloat162 h = __float22bfloat162_rn(make_float2(a, b));   // v_cvt_pk_bf16_f32
  return *reinterpret_cast<unsigned*>(&h);
}
__device__ __forceinline__ ushort_t f2bf(float f) {
  unsigned u = __float_as_uint(f);
  return (ushort_t)((u + 0x7FFFu + ((u >> 16) & 1u)) >> 16);   // RNE scalar
}
__device__ __forceinline__ float bf2f(ushort_t h) {
  return __uint_as_float(((unsigned)h) << 16);
}
__device__ __forceinline__ float sigmoid_(float x) { return 1.0f/(1.0f+__expf(-x)); }
__device__ __forceinline__ float tanh_(float x) { float e=__expf(2.0f*x); return 1.0f-2.0f/(e+1.0f); }

// On-the-fly time projection: proj_frag = old_frag * (1 + d*tw), elementwise.
__device__ __forceinline__ b8 scale8(b8 x, float d, f32x4 t0, f32x4 t1) {
  union { ushort_t u[8]; unsigned q[4]; b8 v; } in, out;
  in.v = x;
  const float tt[8] = {t0[0],t0[1],t0[2],t0[3], t1[0],t1[1],t1[2],t1[3]};
#pragma unroll
  for (int j = 0; j < 4; ++j) {
    float a = bf2f(in.u[2*j]);
    float b = bf2f(in.u[2*j+1]);
    a = fmaf(a, d*tt[2*j],   a);
    b = fmaf(b, d*tt[2*j+1], b);
    out.q[j] = pk2bf(a, b);
  }
  return out.v;
}

// ---- LDS: 149.5 KB, 1 block/CU. PU/PI/QU are NOT staged (computed on the fly
// from OU/OI + d + tw). HI aliases FE's space after item-gi is done with FE.
struct __align__(16) SLds {
  ushort_t OU[EV][128];   // 32KB old_user
  ushort_t OI[EV][128];   // 32KB old_item
  ushort_t FE[EV][192];   // 48KB features -> HI alias (first 32KB) after item gi
  ushort_t HU[EV][128];   // 32KB h'_u
  float TW[128];          // time_w
  float DU[EV], DI[EV], DQ[EV];
};

extern "C" __global__ void prep_weights(
    const float* __restrict__ u_wih, const float* __restrict__ u_whh,
    const float* __restrict__ i_wih, const float* __restrict__ i_whh,
    const float* __restrict__ gate_w, const float* __restrict__ pred_w,
    ushort_t* __restrict__ ws)
{
  const int stride = gridDim.x * blockDim.x;
  const int tid = blockIdx.x * blockDim.x + threadIdx.x;
  for (int i = tid; i < U_SZ; i += stride) {
    const int nt = i / (U_KT*FRAG);
    const int r1 = i - nt*(U_KT*FRAG);
    const int kt = r1 / FRAG;
    const int e  = r1 - kt*FRAG;
    const int l  = e >> 3, j = e & 7;
    const int n  = nt*16 + (l & 15);
    const int k  = (l >> 4)*8 + j;
    float vu, vi;
    if (kt < 14) {
      const int kk = kt*32 + k;
      vu = (kk < 428) ? u_wih[(size_t)n*428 + kk] : 0.0f;
      vi = (kk < 428) ? i_wih[(size_t)n*428 + kk] : 0.0f;
    } else {
      const int kk = (kt - 14)*32 + k;
      vu = u_whh[(size_t)n*128 + kk];
      vi = i_whh[(size_t)n*128 + kk];
    }
    ws[PU_OFF + i] = f2bf(vu);
    ws[PI_OFF + i] = f2bf(vi);
  }
  for (int i = tid; i < G_SZ; i += stride) {
    const int nt = i / (8*FRAG);
    const int r1 = i - nt*(8*FRAG);
    const int kt = r1 / FRAG;
    const int e  = r1 - kt*FRAG;
    const int l  = e >> 3, j = e & 7;
    const int n  = nt*16 + (l & 15);
    const int kk = kt*32 + (l >> 4)*8 + j;
    ws[PG_OFF + i] = f2bf(gate_w[(size_t)n*256 + kk]);
  }
  for (int i = tid; i < P_SZ; i += stride) {
    const int nt = i / (4*FRAG);
    const int r1 = i - nt*(4*FRAG);
    const int kt = r1 / FRAG;
    const int e  = r1 - kt*FRAG;
    const int l  = e >> 3, j = e & 7;
    const int n  = nt*16 + (l & 15);
    const int kk = kt*32 + (l >> 4)*8 + j;
    ws[PP_OFF + i] = f2bf(pred_w[(size_t)n*128 + kk]);
  }
}

extern "C" __global__ void __launch_bounds__(512, 2)
jodie_main(const int* __restrict__ user_ids, const int* __restrict__ item_ids,
           const float* __restrict__ timestamps, const float* __restrict__ features,
           const int* __restrict__ query_time, const float* __restrict__ memv,
           const float* __restrict__ last_time, const float* __restrict__ time_w,
           const float* __restrict__ u_bih, const float* __restrict__ u_bhh,
           const float* __restrict__ i_bih, const float* __restrict__ i_bhh,
           const float* __restrict__ gate_b, const float* __restrict__ pred_b,
           const ushort_t* __restrict__ ws, float* __restrict__ d_out)
{
  __shared__ SLds s;
  ushort_t (*HI)[128] = (ushort_t (*)[128])(&s.FE[0][0]);   // alias (dead FE)
  const int t  = threadIdx.x;
  const int e0 = blockIdx.x * EV;

  // ---- stage: OU/OI tiles + d scalars + TW + FE (no proj tiles!) ----
  if (t < 32) *(float4*)&s.TW[t*4] = *(const float4*)&time_w[t*4];
  {
    const int c8 = (t & 15) * 8;
    const float qt = (float)query_time[0];
#pragma unroll
    for (int ep = 0; ep < 4; ++ep) {
      const int e  = ep*32 + (t >> 4);
      const int ge = e0 + e;
      const int u   = NTLI(&user_ids[ge]);
      const int itn = NTLI(&item_ids[ge]) + CNU;
      const float ts = NTLI(&timestamps[ge]);
      const float lu = NTLI(&last_time[u]);
      const float li = NTLI(&last_time[itn]);
      if ((t & 15) == 0) {
        s.DU[e] = ts - lu;
        s.DI[e] = ts - li;
        s.DQ[e] = qt - lu;
      }
      const f32x4 ou0 = NTL4(&memv[(size_t)u  *CE + c8]);
      const f32x4 ou1 = NTL4(&memv[(size_t)u  *CE + c8 + 4]);
      const f32x4 oi0 = NTL4(&memv[(size_t)itn*CE + c8]);
      const f32x4 oi1 = NTL4(&memv[(size_t)itn*CE + c8 + 4]);
      union { unsigned q[4]; b8 v; } hu, hi;
      hu.q[0] = pk2bf(ou0[0], ou0[1]);  hu.q[1] = pk2bf(ou0[2], ou0[3]);
      hu.q[2] = pk2bf(ou1[0], ou1[1]);  hu.q[3] = pk2bf(ou1[2], ou1[3]);
      hi.q[0] = pk2bf(oi0[0], oi0[1]);  hi.q[1] = pk2bf(oi0[2], oi0[3]);
      hi.q[2] = pk2bf(oi1[0], oi1[1]);  hi.q[3] = pk2bf(oi1[2], oi1[3]);
      *(b8*)&s.OU[e][SWZ(e, c8)] = hu.v;
      *(b8*)&s.OI[e][SWZ(e, c8)] = hi.v;
    }
  }
  for (int i = t; i < EV*43; i += 512) {
    const int e = i / 43, q = i - e*43;
    const f32x4 fv = NTL4(&features[(size_t)(e0 + e)*CF + q*4]);
    union { unsigned q2[2]; b4 v; } fb;
    fb.q2[0] = pk2bf(fv[0], fv[1]);
    fb.q2[1] = pk2bf(fv[2], fv[3]);
    *(b4*)&s.FE[e][SWZ(e, q*4)] = fb.v;
  }
  for (int i = t; i < EV*20; i += 512) {
    const int e = i / 20, c = 172 + (i - e*20);
    s.FE[e][SWZ(e, c)] = 0;
  }
  __syncthreads();   // B1

  const int wv   = t >> 6, l = t & 63;
  const int lrow = l & 15;
  const int lk   = (l >> 4) * 8;
  const int col  = wv*16 + lrow;

  const ushort_t* Wru = ws + PU_OFF + (size_t)(wv     )*U_KT*FRAG + l*8;
  const ushort_t* Wzu = ws + PU_OFF + (size_t)(wv +  8)*U_KT*FRAG + l*8;
  const ushort_t* Wnu = ws + PU_OFF + (size_t)(wv + 16)*U_KT*FRAG + l*8;
  const ushort_t* Wri = ws + PI_OFF + (size_t)(wv     )*U_KT*FRAG + l*8;
  const ushort_t* Wzi = ws + PI_OFF + (size_t)(wv +  8)*U_KT*FRAG + l*8;
  const ushort_t* Wni = ws + PI_OFF + (size_t)(wv + 16)*U_KT*FRAG + l*8;
  const ushort_t* WP  = ws + PP_OFF + (size_t)wv*4*FRAG + l*8;
  const ushort_t* WG  = ws + PG_OFF + (size_t)wv*8*FRAG + l*8;

  // ---- pred: qu = OU*(1+dq*tw) on the fly ----
  {
    const float bp = pred_b[col];
    f4 ap[MT];
#pragma unroll
    for (int m = 0; m < MT; ++m) ap[m] = (f4){bp,bp,bp,bp};
#pragma unroll
    for (int kt = 0; kt < 4; ++kt) {
      b8 fp = *(const b8*)(WP + (size_t)kt*FRAG);
      const f32x4 t0 = *(const f32x4*)&s.TW[32*kt + lk];
      const f32x4 t1 = *(const f32x4*)&s.TW[32*kt + lk + 4];
#pragma unroll
      for (int m = 0; m < MT; ++m) {
        b8 a = scale8(AFRAG(s.OU, m*16 + lrow, 32*kt + lk), s.DQ[m*16 + lrow], t0, t1);
        ap[m] = MFMA16(a, fp, ap[m]);
      }
    }
#pragma unroll
    for (int m = 0; m < MT; ++m)
#pragma unroll
      for (int r4 = 0; r4 < 4; ++r4) {
        const int row = m*16 + (l >> 4)*4 + r4;
        NTS(ap[m][r4], &d_out[(size_t)(e0 + row)*CE + col]);
      }
  }

  // ================= USER GRU =================
  {
    const float br = u_bih[col]     + u_bhh[col];
    const float bz = u_bih[col+128] + u_bhh[col+128];
    const float bn = u_bih[col+256];
    const float bh = u_bhh[col+256];
    f4 ar[MT], az[MT], an8[MT], ah[MT];
#pragma unroll
    for (int m = 0; m < MT; ++m) {
      ar[m] = (f4){br,br,br,br};  az[m] = (f4){bz,bz,bz,bz};
      an8[m] = (f4){bn,bn,bn,bn}; ah[m] = (f4){bh,bh,bh,bh};
    }
    // gi: x_u = [pu | pi | feat]
#pragma unroll
    for (int kt = 0; kt < 4; ++kt) {   // pu from OU
      b8 fr = *(const b8*)(Wru + (size_t)kt*FRAG);
      b8 fz = *(const b8*)(Wzu + (size_t)kt*FRAG);
      b8 fn = *(const b8*)(Wnu + (size_t)kt*FRAG);
      const f32x4 t0 = *(const f32x4*)&s.TW[32*kt + lk];
      const f32x4 t1 = *(const f32x4*)&s.TW[32*kt + lk + 4];
#pragma unroll
      for (int m = 0; m < MT; ++m) {
        b8 a = scale8(AFRAG(s.OU, m*16 + lrow, 32*kt + lk), s.DU[m*16 + lrow], t0, t1);
        ar[m] = MFMA16(a, fr, ar[m]);
        az[m] = MFMA16(a, fz, az[m]);
        an8[m] = MFMA16(a, fn, an8[m]);
      }
    }
#pragma unroll
    for (int kt = 0; kt < 4; ++kt) {   // pi from OI (weight kt+4)
      b8 fr = *(const b8*)(Wru + (size_t)(kt+4)*FRAG);
      b8 fz = *(const b8*)(Wzu + (size_t)(kt+4)*FRAG);
      b8 fn = *(const b8*)(Wnu + (size_t)(kt+4)*FRAG);
      const f32x4 t0 = *(const f32x4*)&s.TW[32*kt + lk];
      const f32x4 t1 = *(const f32x4*)&s.TW[32*kt + lk + 4];
#pragma unroll
      for (int m = 0; m < MT; ++m) {
        b8 a = scale8(AFRAG(s.OI, m*16 + lrow, 32*kt + lk), s.DI[m*16 + lrow], t0, t1);
        ar[m] = MFMA16(a, fr, ar[m]);
        az[m] = MFMA16(a, fz, az[m]);
        an8[m] = MFMA16(a, fn, an8[m]);
      }
    }
#pragma unroll
    for (int kt = 0; kt < 6; ++kt) {   // features (weight kt+8)
      b8 fr = *(const b8*)(Wru + (size_t)(kt+8)*FRAG);
      b8 fz = *(const b8*)(Wzu + (size_t)(kt+8)*FRAG);
      b8 fn = *(const b8*)(Wnu + (size_t)(kt+8)*FRAG);
#pragma unroll
      for (int m = 0; m < MT; ++m) {
        b8 a = AFRAG(s.FE, m*16 + lrow, 32*kt + lk);
        ar[m] = MFMA16(a, fr, ar[m]);
        az[m] = MFMA16(a, fz, az[m]);
        an8[m] = MFMA16(a, fn, an8[m]);
      }
    }
    // gh over OU (weight kt+14); n-side into ah
#pragma unroll
    for (int kt = 0; kt < 4; ++kt) {
      b8 fr = *(const b8*)(Wru + (size_t)(kt+14)*FRAG);
      b8 fz = *(const b8*)(Wzu + (size_t)(kt+14)*FRAG);
      b8 fn = *(const b8*)(Wnu + (size_t)(kt+14)*FRAG);
#pragma unroll
      for (int m = 0; m < MT; ++m) {
        b8 h = AFRAG(s.OU, m*16 + lrow, 32*kt + lk);
        ar[m] = MFMA16(h, fr, ar[m]);
        az[m] = MFMA16(h, fz, az[m]);
        ah[m] = MFMA16(h, fn, ah[m]);
      }
    }
    // ew_u -> HU (dedicated tile; no barrier needed before write)
#pragma unroll
    for (int m = 0; m < MT; ++m)
#pragma unroll
      for (int r4 = 0; r4 < 4; ++r4) {
        const int row = m*16 + (l >> 4)*4 + r4;
        const float rr = sigmoid_(ar[m][r4]);
        const float zz = sigmoid_(az[m][r4]);
        const float nn = tanh_(an8[m][r4] + rr*ah[m][r4]);
        const float h  = bf2f(s.OU[row][SWZ(row, col)]);
        s.HU[row][SWZ(row, col)] = f2bf((1.0f - zz)*nn + zz*h);
      }
  }

  // ================= ITEM GRU =================
  {
    const float br = i_bih[col]     + i_bhh[col];
    const float bz = i_bih[col+128] + i_bhh[col+128];
    const float bn = i_bih[col+256];
    const float bh = i_bhh[col+256];
    f4 ar[MT], az[MT], an8[MT], ah[MT];
#pragma unroll
    for (int m = 0; m < MT; ++m) {
      ar[m] = (f4){br,br,br,br};  az[m] = (f4){bz,bz,bz,bz};
      an8[m] = (f4){bn,bn,bn,bn}; ah[m] = (f4){bh,bh,bh,bh};
    }
    // gi: x_i = [pi | pu | feat]
#pragma unroll
    for (int kt = 0; kt < 4; ++kt) {   // pi from OI
      b8 fr = *(const b8*)(Wri + (size_t)kt*FRAG);
      b8 fz = *(const b8*)(Wzi + (size_t)kt*FRAG);
      b8 fn = *(const b8*)(Wni + (size_t)kt*FRAG);
      const f32x4 t0 = *(const f32x4*)&s.TW[32*kt + lk];
      const f32x4 t1 = *(const f32x4*)&s.TW[32*kt + lk + 4];
#pragma unroll
      for (int m = 0; m < MT; ++m) {
        b8 a = scale8(AFRAG(s.OI, m*16 + lrow, 32*kt + lk), s.DI[m*16 + lrow], t0, t1);
        ar[m] = MFMA16(a, fr, ar[m]);
        az[m] = MFMA16(a, fz, az[m]);
        an8[m] = MFMA16(a, fn, an8[m]);
      }
    }
#pragma unroll
    for (int kt = 0; kt < 4; ++kt) {   // pu from OU (weight kt+4)
      b8 fr = *(const b8*)(Wri + (size_t)(kt+4)*FRAG);
      b8 fz = *(const b8*)(Wzi + (size_t)(kt+4)*FRAG);
      b8 fn = *(const b8*)(Wni + (size_t)(kt+4)*FRAG);
      const f32x4 t0 = *(const f32x4*)&s.TW[32*kt + lk];
      const f32x4 t1 = *(const f32x4*)&s.TW[32*kt + lk + 4];
#pragma unroll
      for (int m = 0; m < MT; ++m) {
        b8 a = scale8(AFRAG(s.OU, m*16 + lrow, 32*kt + lk), s.DU[m*16 + lrow], t0, t1);
        ar[m] = MFMA16(a, fr, ar[m]);
        az[m] = MFMA16(a, fz, az[m]);
        an8[m] = MFMA16(a, fn, an8[m]);
      }
    }
#pragma unroll
    for (int kt = 0; kt < 6; ++kt) {   // features (weight kt+8)
      b8 fr = *(const b8*)(Wri + (size_t)(kt+8)*FRAG);
      b8 fz = *(const b8*)(Wzi + (size_t)(kt+8)*FRAG);
      b8 fn = *(const b8*)(Wni + (size_t)(kt+8)*FRAG);
#pragma unroll
      for (int m = 0; m < MT; ++m) {
        b8 a = AFRAG(s.FE, m*16 + lrow, 32*kt + lk);
        ar[m] = MFMA16(a, fr, ar[m]);
        az[m] = MFMA16(a, fz, az[m]);
        an8[m] = MFMA16(a, fn, an8[m]);
      }
    }
    // gh over OI (weight kt+14)
#pragma unroll
    for (int kt = 0; kt < 4; ++kt) {
      b8 fr = *(const b8*)(Wri + (size_t)(kt+14)*FRAG);
      b8 fz = *(const b8*)(Wzi + (size_t)(kt+14)*FRAG);
      b8 fn = *(const b8*)(Wni + (size_t)(kt+14)*FRAG);
#pragma unroll
      for (int m = 0; m < MT; ++m) {
        b8 h = AFRAG(s.OI, m*16 + lrow, 32*kt + lk);
        ar[m] = MFMA16(h, fr, ar[m]);
        az[m] = MFMA16(h, fz, az[m]);
        ah[m] = MFMA16(h, fn, ah[m]);
      }
    }
    __syncthreads();   // B2: ALL waves done reading FE (item gi) -> HI alias safe
    // ew_i -> HI (FE alias)
#pragma unroll
    for (int m = 0; m < MT; ++m)
#pragma unroll
      for (int r4 = 0; r4 < 4; ++r4) {
        const int row = m*16 + (l >> 4)*4 + r4;
        const float rr = sigmoid_(ar[m][r4]);
        const float zz = sigmoid_(az[m][r4]);
        const float nn = tanh_(an8[m][r4] + rr*ah[m][r4]);
        const float h  = bf2f(s.OI[row][SWZ(row, col)]);
        HI[row][SWZ(row, col)] = f2bf((1.0f - zz)*nn + zz*h);
      }
  }
  __syncthreads();   // B3: HU + HI visible to all waves

  // ---- memory gates: shared gate_w fragments, user+item A streams ----
  {
    const float gb = gate_b[col];
    f4 agu[MT], agi[MT];
#pragma unroll
    for (int m = 0; m < MT; ++m) { agu[m] = (f4){gb,gb,gb,gb}; agi[m] = agu[m]; }
#pragma unroll
    for (int kt = 0; kt < 4; ++kt) {   // [h | .] half
      b8 fg = *(const b8*)(WG + (size_t)kt*FRAG);
#pragma unroll
      for (int m = 0; m < MT; ++m) {
        b8 au = AFRAG(s.OU, m*16 + lrow, 32*kt + lk);
        b8 ai = AFRAG(s.OI, m*16 + lrow, 32*kt + lk);
        agu[m] = MFMA16(au, fg, agu[m]);
        agi[m] = MFMA16(ai, fg, agi[m]);
      }
    }
#pragma unroll
    for (int kt = 0; kt < 4; ++kt) {   // [. | h'] half (weight kt+4)
      b8 fg = *(const b8*)(WG + (size_t)(kt+4)*FRAG);
#pragma unroll
      for (int m = 0; m < MT; ++m) {
        b8 au = AFRAG(s.HU, m*16 + lrow, 32*kt + lk);
        b8 ai = AFRAG(HI,   m*16 + lrow, 32*kt + lk);
        agu[m] = MFMA16(au, fg, agu[m]);
        agi[m] = MFMA16(ai, fg, agi[m]);
      }
    }
    float* __restrict__ outu = d_out + (size_t)CB*CE;
    float* __restrict__ outi = d_out + (size_t)2*CB*CE;
#pragma unroll
    for (int m = 0; m < MT; ++m)
#pragma unroll
      for (int r4 = 0; r4 < 4; ++r4) {
        const int row = m*16 + (l >> 4)*4 + r4;
        const float gu = sigmoid_(agu[m][r4]);
        const float gi = sigmoid_(agi[m][r4]);
        const float hu  = bf2f(s.OU[row][SWZ(row, col)]);
        const float hpu = bf2f(s.HU[row][SWZ(row, col)]);
        const float hi  = bf2f(s.OI[row][SWZ(row, col)]);
        const float hpi = bf2f(HI[row][SWZ(row, col)]);
        NTS(gu*hpu + (1.0f - gu)*hu, &outu[(size_t)(e0 + row)*CE + col]);
        NTS(gi*hpi + (1.0f - gi)*hi, &outi[(size_t)(e0 + row)*CE + col]);
      }
  }
}

extern "C" void kernel_launch(void* const* d_in, const int* in_sizes, int n_in,
                              void* d_out, int out_size, void* d_ws, size_t ws_size,
                              hipStream_t stream) {
  const int*   user_ids   = (const int*)d_in[0];
  const int*   item_ids   = (const int*)d_in[1];
  const float* timestamps = (const float*)d_in[2];
  const float* features   = (const float*)d_in[3];
  const int*   query_time = (const int*)d_in[4];
  const float* memv       = (const float*)d_in[5];
  const float* last_time  = (const float*)d_in[6];
  const float* time_w     = (const float*)d_in[7];
  const float* u_wih = (const float*)d_in[8];
  const float* u_whh = (const float*)d_in[9];
  const float* u_bih = (const float*)d_in[10];
  const float* u_bhh = (const float*)d_in[11];
  const float* i_wih = (const float*)d_in[12];
  const float* i_whh = (const float*)d_in[13];
  const float* i_bih = (const float*)d_in[14];
  const float* i_bhh = (const float*)d_in[15];
  const float* gate_w = (const float*)d_in[16];
  const float* gate_b = (const float*)d_in[17];
  const float* pred_w = (const float*)d_in[18];
  const float* pred_b = (const float*)d_in[19];
  ushort_t* ws = (ushort_t*)d_ws;
  float* out = (float*)d_out;

  prep_weights<<<dim3(256), dim3(256), 0, stream>>>(u_wih, u_whh, i_wih, i_whh,
                                                    gate_w, pred_w, ws);
  jodie_main<<<dim3(CB/EV), dim3(512), 0, stream>>>(user_ids, item_ids, timestamps,
                                                    features, query_time, memv,
                                                    last_time, time_w,
                                                    u_bih, u_bhh, i_bih, i_bhh,
                                                    gate_b, pred_b, ws, out);
}